// Round 8
// baseline (430.723 us; speedup 1.0000x reference)
//
#include <hip/hip_runtime.h>

typedef unsigned short u16;
typedef unsigned int   u32;
typedef __attribute__((ext_vector_type(8))) short bf16x8;
typedef __attribute__((ext_vector_type(4))) float f32x4;
typedef __attribute__((ext_vector_type(2))) unsigned int u32x2;

#define B_ 8
#define T_ 2048
#define M_ 16384          // B*T
#define N_ 3072           // 3*H
#define H_ 1024
#define L_ 64             // scan chunk length
#define NC_ 32            // chunks per sequence (T_/L_)

__device__ __forceinline__ u16 f2bf(float f) {
    union { float f; unsigned u; } v; v.f = f;
    unsigned r = v.u + 0x7FFFu + ((v.u >> 16) & 1u);   // RNE
    return (u16)(r >> 16);
}
__device__ __forceinline__ float bf2f(u16 s) {
    union { unsigned u; float f; } v; v.u = ((unsigned)s) << 16;
    return v.f;
}
__device__ __forceinline__ float sigm(float x) {
    return 1.f / (1.f + __expf(-x));
}

__device__ __forceinline__ void gload_lds16(const void* g, void* l) {
    __builtin_amdgcn_global_load_lds(
        (const __attribute__((address_space(1))) unsigned int*)g,
        (__attribute__((address_space(3))) unsigned int*)l,
        16, 0, 0);
}

// Build bf16 x1 [16384][1600] = concat(pa, st, md) zero-padded 1591..1600
__device__ __forceinline__ float cc_el(int d, const float* pam, const float* stm,
                                       const float* mdm) {
    if (d < 695)  return pam[d];
    if (d < 1507) return stm[d - 695];
    if (d < 1591) return mdm[d - 1507];
    return 0.f;
}
__global__ void concat_cast(const float* __restrict__ pa, const float* __restrict__ st,
                            const float* __restrict__ md, u16* __restrict__ x) {
    const int m = blockIdx.x;
    const float* pam = pa + (size_t)m * 695;
    const float* stm = st + (size_t)m * 812;
    const float* mdm = md + (size_t)m * 84;
    u32* xm = (u32*)(x + (size_t)m * 1600);
    for (int d2 = threadIdx.x; d2 < 800; d2 += 256) {
        const float v0 = cc_el(d2 * 2,     pam, stm, mdm);
        const float v1 = cc_el(d2 * 2 + 1, pam, stm, mdm);
        xm[d2] = (u32)f2bf(v0) | ((u32)f2bf(v1) << 16);
    }
}

// Wt[n][k] = bf16(W[k][n]), K rows valid, zero-pad to Kp
__global__ void wtrans(const float* __restrict__ W, u16* __restrict__ Wt, int K, int Kp) {
    __shared__ float tile[32][33];
    const int n0 = blockIdx.x << 5;
    const int k0 = blockIdx.y << 5;
    const int tx = threadIdx.x & 31, ty = threadIdx.x >> 5;   // 32 x 8
    #pragma unroll
    for (int i = 0; i < 32; i += 8) {
        int k = k0 + ty + i;
        tile[ty + i][tx] = (k < K) ? W[(size_t)k * N_ + n0 + tx] : 0.f;
    }
    __syncthreads();
    #pragma unroll
    for (int i = 0; i < 32; i += 8) {
        int n = n0 + ty + i;
        Wt[(size_t)n * Kp + k0 + tx] = f2bf(tile[tx][ty + i]);
    }
}

// ---- 256x128 GEMM, 4 waves (2m x 2n), BK=32, 3-deep LDS ring, 2 blocks/CU ----
// Ring slot (24KB = 12288 u16): A[256r][32k] (8192 u16) + B[128r][32k] (4096 u16).
// Per kt: stage kt+2 into buf[(kt+2)%3] (6 x gload_lds 1KB), 12 frag ds_reads of
// buf[kt%3], 32 MFMA, vmcnt(6) (counted: kt+1's buffer landed, never drains to 0),
// lgkmcnt(0), ONE barrier.  16B k-slots swizzled slot' = slot ^ ((row>>1)&3),
// inverse applied on the global source (LDS writes linear for global_load_lds);
// frag-read pattern = R4/R6's verified zero-conflict layout.  MFMA swapped:
// mfma(bfr, af) -> D: m = lane&15 (A side), n = (lane>>4)*4+reg (B side).
// Epilogue: bf16 pack -> swizzled [256][128] LDS image -> coalesced row stores.
__global__ __launch_bounds__(256, 2)
void gemm8p(const u16* __restrict__ A, const u16* __restrict__ Bt,
            const float* __restrict__ bias, u16* __restrict__ Y,
            int Kp, int NK, int NBN) {
    __shared__ u16 lds[36864];   // 72 KB
    const int tid = threadIdx.x;
    const int w = tid >> 6, l = tid & 63;
    const int wm = w >> 1, wn = w & 1;

    // XCD-bijective swizzle (gridDim.x % 8 == 0)
    const int cpx = gridDim.x >> 3;
    const int xg = (blockIdx.x & 7) * cpx + (blockIdx.x >> 3);
    const int bm = xg / NBN, bn = xg % NBN;
    const int brow = bm << 8, bcol = bn << 7;

    // staging: per instr 16 rows (lane l -> row +(l>>2), 16B slot l&3);
    // inverse-swizzled global slot = (l&3) ^ ((l>>3)&3)
    const int gslot = (l & 3) ^ ((l >> 3) & 3);
    const u16* pA = A  + (size_t)(brow + (w << 4) + (l >> 2)) * Kp + gslot * 8;
    const u16* pB = Bt + (size_t)(bcol + (w << 4) + (l >> 2)) * Kp + gslot * 8;

#define STG_A(r, kt) do {                                                           \
    gload_lds16(pA + (size_t)(kt) * 32,                    &lds[(r) * 12288 + (w << 9)]);        \
    gload_lds16(pA + (size_t)(kt) * 32 +  64 * (size_t)Kp, &lds[(r) * 12288 + 2048 + (w << 9)]); \
    gload_lds16(pA + (size_t)(kt) * 32 + 128 * (size_t)Kp, &lds[(r) * 12288 + 4096 + (w << 9)]); \
    gload_lds16(pA + (size_t)(kt) * 32 + 192 * (size_t)Kp, &lds[(r) * 12288 + 6144 + (w << 9)]); \
} while (0)
#define STG_B(r, kt) do {                                                           \
    gload_lds16(pB + (size_t)(kt) * 32,                   &lds[(r) * 12288 + 8192 + (w << 9)]);         \
    gload_lds16(pB + (size_t)(kt) * 32 + 64 * (size_t)Kp, &lds[(r) * 12288 + 8192 + 2048 + (w << 9)]);  \
} while (0)

    // frag read (verified zero-conflict): row l&15, slot (l>>4)^((l>>1)&3)
    const int fl = ((l & 15) << 5) + ((((l >> 4) ^ ((l >> 1) & 3)) & 3) << 3);
    const int abase = wm << 12;            // wm*128 rows * 32
    const int bbase = 8192 + (wn << 11);   // B region + wn*64 rows * 32

    f32x4 acc[8][4] = {};

    // prologue: buffers 0,1  (NK >= 2 always)
    STG_A(0, 0); STG_B(0, 0);
    STG_A(1, 1); STG_B(1, 1);
    asm volatile("s_waitcnt vmcnt(6)" ::: "memory");   // buffer 0 landed
    __builtin_amdgcn_s_barrier();
    asm volatile("" ::: "memory");

    for (int kt = 0; kt < NK; ++kt) {
        const int cur = kt % 3;
        const int nb  = (kt + 2) % 3;
        const int nxt = (kt + 2 < NK) ? kt + 2 : kt;   // src clamp; dest buffer dead
        STG_A(nb, nxt); STG_B(nb, nxt);

        bf16x8 afr[8], bfr[4];
        const int cb = cur * 12288;
        #pragma unroll
        for (int mf = 0; mf < 8; ++mf)
            afr[mf] = *reinterpret_cast<const bf16x8*>(&lds[cb + abase + (mf << 9) + fl]);
        #pragma unroll
        for (int nf = 0; nf < 4; ++nf)
            bfr[nf] = *reinterpret_cast<const bf16x8*>(&lds[cb + bbase + (nf << 9) + fl]);

        __builtin_amdgcn_s_setprio(1);
        #pragma unroll
        for (int mf = 0; mf < 8; ++mf)
            #pragma unroll
            for (int nf = 0; nf < 4; ++nf)
                acc[mf][nf] = __builtin_amdgcn_mfma_f32_16x16x32_bf16(
                    bfr[nf], afr[mf], acc[mf][nf], 0, 0, 0);
        __builtin_amdgcn_s_setprio(0);

        asm volatile("s_waitcnt vmcnt(6)" ::: "memory");   // kt+1's buffer landed
        asm volatile("s_waitcnt lgkmcnt(0)" ::: "memory"); // my reads drained
        __builtin_amdgcn_s_barrier();
        asm volatile("" ::: "memory");
    }

    // ---- epilogue via LDS transpose ----
    asm volatile("s_waitcnt vmcnt(0)" ::: "memory");   // drain tail stages
    __builtin_amdgcn_s_barrier();

    // pack acc+bias -> LDS image [256 m][128 n] bf16; 16B-unit idx16' = idx16 ^ ((m&7)<<1)
    const int nq = (l >> 4) << 2;                      // 0,4,8,12
    float4 bv4[4];
    #pragma unroll
    for (int nf = 0; nf < 4; ++nf)
        bv4[nf] = *reinterpret_cast<const float4*>(&bias[bcol + (wn << 6) + nf * 16 + nq]);
    #pragma unroll
    for (int mf = 0; mf < 8; ++mf) {
        const int mrow = (wm << 7) + (mf << 4) + (l & 15);
        #pragma unroll
        for (int nf = 0; nf < 4; ++nf) {
            const int nloc = (wn << 6) + nf * 16 + nq;
            u32x2 p;
            p.x = (u32)f2bf(acc[mf][nf][0] + bv4[nf].x) |
                  ((u32)f2bf(acc[mf][nf][1] + bv4[nf].y) << 16);
            p.y = (u32)f2bf(acc[mf][nf][2] + bv4[nf].z) |
                  ((u32)f2bf(acc[mf][nf][3] + bv4[nf].w) << 16);
            const int idx16 = (nloc >> 3) ^ ((mrow & 7) << 1);
            const int boff = (mrow << 8) + (idx16 << 4) + ((nloc >> 2) & 1) * 8;
            *reinterpret_cast<u32x2*>(&((char*)lds)[boff]) = p;
        }
    }
    asm volatile("s_waitcnt lgkmcnt(0)" ::: "memory");
    __builtin_amdgcn_s_barrier();

    // coalesced stores: per instr 4 rows x 256B (lane l -> row l>>4, unit l&15)
    #pragma unroll
    for (int ip = 0; ip < 16; ++ip) {
        const int mrow = (w << 6) + (ip << 2) + (l >> 4);
        const int idx16 = (l & 15) ^ ((mrow & 7) << 1);
        const bf16x8 v = *reinterpret_cast<const bf16x8*>(
            &((char*)lds)[(mrow << 8) + (idx16 << 4)]);
        *reinterpret_cast<bf16x8*>(&Y[(size_t)(brow + mrow) * N_ + bcol + (l & 15) * 8]) = v;
    }
#undef STG_A
#undef STG_B
}

// ---- chunked scan ----
__global__ void scan_p1(const u16* __restrict__ y, float* __restrict__ aprod,
                        float* __restrict__ cend) {
    const int hb = blockIdx.x & 1;
    const int chunk = (blockIdx.x >> 1) & (NC_ - 1);
    const int b = blockIdx.x >> 6;
    const int h = (hb << 9) + (threadIdx.x << 1);
    const u16* yb = y + ((size_t)b * T_ + (size_t)chunk * L_) * N_;
    float a0 = 1.f, a1 = 1.f, c0 = 0.f, c1 = 0.f;
    #pragma unroll 4
    for (int t = 0; t < L_; ++t) {
        const u32 zz = *reinterpret_cast<const u32*>(&yb[t * N_ + h]);
        const u32 ff = *reinterpret_cast<const u32*>(&yb[t * N_ + H_ + h]);
        const float f0 = sigm(bf2f((u16)ff));
        const float f1 = sigm(bf2f((u16)(ff >> 16)));
        const float z0 = fmaxf(bf2f((u16)zz), 0.f);
        const float z1 = fmaxf(bf2f((u16)(zz >> 16)), 0.f);
        c0 = f0 * z0 + (1.f - f0) * c0;  a0 *= (1.f - f0);
        c1 = f1 * z1 + (1.f - f1) * c1;  a1 *= (1.f - f1);
    }
    const size_t idx = ((size_t)b * NC_ + chunk) * H_ + h;
    *reinterpret_cast<float2*>(&aprod[idx]) = make_float2(a0, a1);
    *reinterpret_cast<float2*>(&cend[idx])  = make_float2(c0, c1);
}

__global__ void scan_p2(const float* __restrict__ aprod, const float* __restrict__ cend,
                        float* __restrict__ cin, float* __restrict__ hout, int layer) {
    const int b = blockIdx.x >> 2;
    const int h = ((blockIdx.x & 3) << 8) + threadIdx.x;
    float c = 0.f;
    #pragma unroll
    for (int k = 0; k < NC_; ++k) {
        const size_t idx = ((size_t)b * NC_ + k) * H_ + h;
        cin[idx] = c;
        c = aprod[idx] * c + cend[idx];
    }
    hout[(size_t)(((b << 1) + layer) << 10) + h] = c;
}

__global__ void scan_p3(const u16* __restrict__ y, const float* __restrict__ cin,
                        void* __restrict__ xout, int layer) {
    const int hb = blockIdx.x & 1;
    const int chunk = (blockIdx.x >> 1) & (NC_ - 1);
    const int b = blockIdx.x >> 6;
    const int h = (hb << 9) + (threadIdx.x << 1);
    const u16* yb = y + ((size_t)b * T_ + (size_t)chunk * L_) * N_;
    const size_t cidx = ((size_t)b * NC_ + chunk) * H_ + h;
    const float2 cv = *reinterpret_cast<const float2*>(&cin[cidx]);
    float c0 = cv.x, c1 = cv.y;
    u32*    xo_bf = (u32*)xout;
    float2* xo_f  = (float2*)xout;
    const size_t obase = ((size_t)b * T_ + (size_t)chunk * L_) * H_ + h;
    #pragma unroll 4
    for (int t = 0; t < L_; ++t) {
        const u32 zz = *reinterpret_cast<const u32*>(&yb[t * N_ + h]);
        const u32 ff = *reinterpret_cast<const u32*>(&yb[t * N_ + H_ + h]);
        const u32 oo = *reinterpret_cast<const u32*>(&yb[t * N_ + 2 * H_ + h]);
        const float f0 = sigm(bf2f((u16)ff));
        const float f1 = sigm(bf2f((u16)(ff >> 16)));
        const float z0 = fmaxf(bf2f((u16)zz), 0.f);
        const float z1 = fmaxf(bf2f((u16)(zz >> 16)), 0.f);
        c0 = f0 * z0 + (1.f - f0) * c0;
        c1 = f1 * z1 + (1.f - f1) * c1;
        const float o0 = sigm(bf2f((u16)oo)) * c0;
        const float o1 = sigm(bf2f((u16)(oo >> 16))) * c1;
        const size_t oi = obase + (size_t)t * H_;
        if (layer) xo_f[oi >> 1] = make_float2(o0, o1);
        else       xo_bf[oi >> 1] = (u32)f2bf(o0) | ((u32)f2bf(o1) << 16);
    }
}

extern "C" void kernel_launch(void* const* d_in, const int* in_sizes, int n_in,
                              void* d_out, int out_size, void* d_ws, size_t ws_size,
                              hipStream_t stream) {
    const float* pa = (const float*)d_in[0];
    const float* st = (const float*)d_in[1];
    const float* md = (const float*)d_in[2];
    const float* W1 = (const float*)d_in[3];
    const float* b1 = (const float*)d_in[4];
    const float* W2 = (const float*)d_in[5];
    const float* b2 = (const float*)d_in[6];
    float* out = (float*)d_out;

    char* ws = (char*)d_ws;
    const size_t y_bytes = (size_t)M_ * N_ * 2;          // 100.7 MB
    const size_t x_bytes = (size_t)M_ * 1600 * 2;        // 52.4 MB
    u16* y  = (u16*)ws;
    u16* x  = (u16*)(ws + y_bytes);
    u16* Wt = (u16*)(ws + y_bytes + x_bytes);            // 9.8 MB
    char* scr = ws + y_bytes + (size_t)M_ * H_ * 2;
    const size_t sarr = (size_t)B_ * NC_ * H_ * 4;       // 1 MB each
    float* aprod = (float*)scr;
    float* cend  = (float*)(scr + sarr);
    float* cin   = (float*)(scr + 2 * sarr);

    float* hout = out + (size_t)M_ * H_;

    const int grid_g = (M_ / 256) * (N_ / 128);          // 64*24 = 1536 (%8==0)

    // ---- layer 1 ----
    concat_cast<<<M_, 256, 0, stream>>>(pa, st, md, x);
    wtrans<<<dim3(N_ / 32, 50), 256, 0, stream>>>(W1, Wt, 1591, 1600);
    gemm8p<<<grid_g, 256, 0, stream>>>(x, Wt, b1, y, 1600, 50, N_ / 128);
    scan_p1<<<B_ * NC_ * 2, 256, 0, stream>>>(y, aprod, cend);
    scan_p2<<<32, 256, 0, stream>>>(aprod, cend, cin, hout, 0);
    scan_p3<<<B_ * NC_ * 2, 256, 0, stream>>>(y, cin, x, 0);   // bf16 x2 into x

    // ---- layer 2 ----
    wtrans<<<dim3(N_ / 32, 32), 256, 0, stream>>>(W2, Wt, 1024, 1024);
    gemm8p<<<grid_g, 256, 0, stream>>>(x, Wt, b2, y, 1024, 32, N_ / 128);
    scan_p1<<<B_ * NC_ * 2, 256, 0, stream>>>(y, aprod, cend);
    scan_p2<<<32, 256, 0, stream>>>(aprod, cend, cin, hout, 1);
    scan_p3<<<B_ * NC_ * 2, 256, 0, stream>>>(y, cin, out, 1);
}

// Round 9
// 410.306 us; speedup vs baseline: 1.0498x; 1.0498x over previous
//
#include <hip/hip_runtime.h>

typedef unsigned short u16;
typedef unsigned int   u32;
typedef __attribute__((ext_vector_type(8))) short bf16x8;
typedef __attribute__((ext_vector_type(4))) float f32x4;
typedef __attribute__((ext_vector_type(2))) unsigned int u32x2;

#define B_ 8
#define T_ 2048
#define M_ 16384          // B*T
#define N_ 3072           // 3*H
#define H_ 1024
#define L_ 32             // scan chunk length
#define NC_ 64            // chunks per sequence (T_/L_)

__device__ __forceinline__ u16 f2bf(float f) {
    union { float f; unsigned u; } v; v.f = f;
    unsigned r = v.u + 0x7FFFu + ((v.u >> 16) & 1u);   // RNE
    return (u16)(r >> 16);
}
__device__ __forceinline__ float bf2f(u16 s) {
    union { unsigned u; float f; } v; v.u = ((unsigned)s) << 16;
    return v.f;
}
__device__ __forceinline__ float sigm(float x) {
    return 1.f / (1.f + __expf(-x));
}

__device__ __forceinline__ void gload_lds16(const void* g, void* l) {
    __builtin_amdgcn_global_load_lds(
        (const __attribute__((address_space(1))) unsigned int*)g,
        (__attribute__((address_space(3))) unsigned int*)l,
        16, 0, 0);
}

// Build bf16 x1 [16384][1600] = concat(pa, st, md) zero-padded 1591..1600
__device__ __forceinline__ float cc_el(int d, const float* pam, const float* stm,
                                       const float* mdm) {
    if (d < 695)  return pam[d];
    if (d < 1507) return stm[d - 695];
    if (d < 1591) return mdm[d - 1507];
    return 0.f;
}
__global__ void concat_cast(const float* __restrict__ pa, const float* __restrict__ st,
                            const float* __restrict__ md, u16* __restrict__ x) {
    const int m = blockIdx.x;
    const float* pam = pa + (size_t)m * 695;
    const float* stm = st + (size_t)m * 812;
    const float* mdm = md + (size_t)m * 84;
    u32* xm = (u32*)(x + (size_t)m * 1600);
    for (int d2 = threadIdx.x; d2 < 800; d2 += 256) {
        const float v0 = cc_el(d2 * 2,     pam, stm, mdm);
        const float v1 = cc_el(d2 * 2 + 1, pam, stm, mdm);
        xm[d2] = (u32)f2bf(v0) | ((u32)f2bf(v1) << 16);
    }
}

// Wt[n][k] = bf16(W[k][n]), K rows valid, zero-pad to Kp
__global__ void wtrans(const float* __restrict__ W, u16* __restrict__ Wt, int K, int Kp) {
    __shared__ float tile[32][33];
    const int n0 = blockIdx.x << 5;
    const int k0 = blockIdx.y << 5;
    const int tx = threadIdx.x & 31, ty = threadIdx.x >> 5;   // 32 x 8
    #pragma unroll
    for (int i = 0; i < 32; i += 8) {
        int k = k0 + ty + i;
        tile[ty + i][tx] = (k < K) ? W[(size_t)k * N_ + n0 + tx] : 0.f;
    }
    __syncthreads();
    #pragma unroll
    for (int i = 0; i < 32; i += 8) {
        int n = n0 + ty + i;
        Wt[(size_t)n * Kp + k0 + tx] = f2bf(tile[tx][ty + i]);
    }
}

// ---- 256x256 GEMM, BK=32, 4-deep LDS ring, 2 phases/K-tile, 16x16x32 MFMA ----
// (R6 structure, measured best: 153us/dispatch, MfmaUtil 46, conflicts 786K.)
// LDS: 4 buffers x (A[256r][32k] 16KB + B 16KB) = 128KB.  Stage buffer kt+3
// during kt (A at ph0, B at ph1); vmcnt(8) once per K-tile (counted, never 0
// in loop).  ONE barrier per phase; lgkmcnt(0) drained BEFORE the barrier.
// 16B k-slots XOR-swizzled with swz(row)=(row>>1)&3 (inverse on global source;
// LDS writes stay linear for global_load_lds); frag-read pattern = verified
// zero-conflict 16x16 layout.  MFMA operands swapped:
// mfma(bfr, af) -> D: m = lane&15 (A side), n = (lane>>4)*4+reg (B side).
// Epilogue: pack bf16 into a [256][256] swizzled LDS image (ring is dead),
// then fully-coalesced row stores (each wave instr = 2 rows x 512B).
__global__ __launch_bounds__(512, 1)
void gemm8p(const u16* __restrict__ A, const u16* __restrict__ Bt,
            const float* __restrict__ bias, u16* __restrict__ Y,
            int Kp, int NK, int NBN) {
    __shared__ u16 lds[65536];   // 128 KB
    const int tid = threadIdx.x;
    const int w = tid >> 6, l = tid & 63;
    const int wm = w >> 2, wn = w & 3;

    // XCD-bijective swizzle (gridDim.x % 8 == 0)
    const int cpx = gridDim.x >> 3;
    const int xg = (blockIdx.x & 7) * cpx + (blockIdx.x >> 3);
    const int bm = xg / NBN, bn = xg % NBN;
    const int brow = bm << 8, bcol = bn << 8;

    // staging: wave w owns rows w*32..w*32+31; per instr 16 rows (lane ->
    // row +(l>>2), 16B slot l&3); inverse-swizzled global slot
    const int srow = (w << 5) + (l >> 2);
    const int gslot = (l & 3) ^ ((l >> 3) & 3);
    const u16* ga = A  + (size_t)(brow + srow) * Kp + gslot * 8;
    const u16* gb = Bt + (size_t)(bcol + srow) * Kp + gslot * 8;
    const int ldst = w << 10;    // u16 offset of wave's 2KB staging chunk

    // frag read (verified zero-conflict): row l&15, slot (l>>4)^((l>>1)&3)
    const int fl = ((l & 15) << 5) + ((((l >> 4) ^ ((l >> 1) & 3)) & 3) << 3);
    const int abase = wm << 12;            // (wm*128 rows)*32 u16
    const int bbase = 8192 + (wn << 11);   // B half + (wn*64 rows)*32

#define STG_A(r, kt) do {                                                      \
    gload_lds16(ga + (size_t)(kt) * 32,                   &lds[((r) << 14) + ldst]);        \
    gload_lds16(ga + (size_t)(kt) * 32 + 16 * (size_t)Kp, &lds[((r) << 14) + ldst + 512]);  \
} while (0)
#define STG_B(r, kt) do {                                                      \
    gload_lds16(gb + (size_t)(kt) * 32,                   &lds[((r) << 14) + 8192 + ldst]);       \
    gload_lds16(gb + (size_t)(kt) * 32 + 16 * (size_t)Kp, &lds[((r) << 14) + 8192 + ldst + 512]); \
} while (0)

    f32x4 acc[8][4] = {};
    bf16x8 bfr[4];

    // prologue: buffers 0,1,2
    STG_A(0, 0); STG_B(0, 0);
    STG_A(1, 1); STG_B(1, 1);
    STG_A(2, 2); STG_B(2, 2);
    asm volatile("s_waitcnt vmcnt(8)" ::: "memory");   // buffer 0 landed
    __builtin_amdgcn_s_barrier();
    asm volatile("" ::: "memory");

#define PH(CIH, LOADB, STAGECODE, WAITCODE) do {                               \
    bf16x8 af[4];                                                              \
    const int cb = cur << 14;                                                  \
    _Pragma("unroll")                                                          \
    for (int mi = 0; mi < 4; ++mi)                                             \
        af[mi] = *reinterpret_cast<const bf16x8*>(                             \
            &lds[cb + abase + (((CIH) * 4 + mi) << 9) + fl]);                  \
    if (LOADB) {                                                               \
        _Pragma("unroll")                                                      \
        for (int ni = 0; ni < 4; ++ni)                                         \
            bfr[ni] = *reinterpret_cast<const bf16x8*>(                        \
                &lds[cb + bbase + (ni << 9) + fl]);                            \
    }                                                                          \
    STAGECODE;                                                                 \
    WAITCODE;                                                                  \
    __builtin_amdgcn_s_barrier();                                              \
    __builtin_amdgcn_sched_barrier(0);                                         \
    __builtin_amdgcn_s_setprio(1);                                             \
    _Pragma("unroll")                                                          \
    for (int mi = 0; mi < 4; ++mi)                                             \
        _Pragma("unroll")                                                      \
        for (int ni = 0; ni < 4; ++ni)                                         \
            acc[(CIH) * 4 + mi][ni] = __builtin_amdgcn_mfma_f32_16x16x32_bf16( \
                bfr[ni], af[mi], acc[(CIH) * 4 + mi][ni], 0, 0, 0);            \
    __builtin_amdgcn_s_setprio(0);                                             \
    __builtin_amdgcn_sched_barrier(0);                                         \
} while (0)

    for (int kt = 0; kt < NK; ++kt) {
        const int cur = kt & 3;
        const int nxt = (kt + 3 < NK) ? kt + 3 : kt;   // src clamp; dest buffer is dead
        const int nb = (kt + 3) & 3;
        PH(0, 1, { STG_A(nb, nxt); },
                 { asm volatile("s_waitcnt lgkmcnt(0)" ::: "memory"); });
        PH(1, 0, { STG_B(nb, nxt); },
                 { asm volatile("s_waitcnt vmcnt(8) lgkmcnt(0)" ::: "memory"); });
    }

    // ---- epilogue via LDS transpose ----
    asm volatile("s_waitcnt vmcnt(0)" ::: "memory");   // tail stages landed
    __builtin_amdgcn_s_barrier();                      // all waves drained

    // pack acc+bias -> LDS [256 rows][32 x 16B col16 units], col16 ^= row&7
    const int nloc0 = (wn << 6) + ((l >> 4) << 2);
    float4 bv4[4];
    #pragma unroll
    for (int nf = 0; nf < 4; ++nf)
        bv4[nf] = *reinterpret_cast<const float4*>(&bias[bcol + nloc0 + nf * 16]);
    #pragma unroll
    for (int ci = 0; ci < 8; ++ci) {
        const int mrow = (wm << 7) + ((ci >> 2) << 6) + ((ci & 3) << 4) + (l & 15);
        #pragma unroll
        for (int nf = 0; nf < 4; ++nf) {
            const int nloc = nloc0 + nf * 16;
            u32x2 p;
            p.x = (u32)f2bf(acc[ci][nf][0] + bv4[nf].x) |
                  ((u32)f2bf(acc[ci][nf][1] + bv4[nf].y) << 16);
            p.y = (u32)f2bf(acc[ci][nf][2] + bv4[nf].z) |
                  ((u32)f2bf(acc[ci][nf][3] + bv4[nf].w) << 16);
            const int off = (mrow << 8) + (((nloc >> 3) ^ (mrow & 7)) << 3) +
                            ((nloc >> 2) & 1) * 4;
            *reinterpret_cast<u32x2*>(&lds[off]) = p;
        }
    }
    asm volatile("s_waitcnt lgkmcnt(0)" ::: "memory");
    __builtin_amdgcn_s_barrier();

    // coalesced stores: per instr, lanes 0-31 -> row r (512B), lanes 32-63 -> r+1
    #pragma unroll
    for (int rp = 0; rp < 16; ++rp) {
        const int row = (w << 5) + (rp << 1) + (l >> 5);
        const int c16 = l & 31;
        const bf16x8 v = *reinterpret_cast<const bf16x8*>(
            &lds[(row << 8) + ((c16 ^ (row & 7)) << 3)]);
        *reinterpret_cast<bf16x8*>(&Y[(size_t)(brow + row) * N_ + bcol + c16 * 8]) = v;
    }
#undef PH
#undef STG_A
#undef STG_B
}

// ---- chunked scan (L=32, NC=64: 1024 blocks -> 4 waves/SIMD for TLP) ----
__global__ void scan_p1(const u16* __restrict__ y, float* __restrict__ aprod,
                        float* __restrict__ cend) {
    const int hb = blockIdx.x & 1;
    const int chunk = (blockIdx.x >> 1) & (NC_ - 1);
    const int b = blockIdx.x >> 7;
    const int h = (hb << 9) + (threadIdx.x << 1);
    const u16* yb = y + ((size_t)b * T_ + (size_t)chunk * L_) * N_;
    float a0 = 1.f, a1 = 1.f, c0 = 0.f, c1 = 0.f;
    #pragma unroll 4
    for (int t = 0; t < L_; ++t) {
        const u32 zz = *reinterpret_cast<const u32*>(&yb[t * N_ + h]);
        const u32 ff = *reinterpret_cast<const u32*>(&yb[t * N_ + H_ + h]);
        const float f0 = sigm(bf2f((u16)ff));
        const float f1 = sigm(bf2f((u16)(ff >> 16)));
        const float z0 = fmaxf(bf2f((u16)zz), 0.f);
        const float z1 = fmaxf(bf2f((u16)(zz >> 16)), 0.f);
        c0 = f0 * z0 + (1.f - f0) * c0;  a0 *= (1.f - f0);
        c1 = f1 * z1 + (1.f - f1) * c1;  a1 *= (1.f - f1);
    }
    const size_t idx = ((size_t)b * NC_ + chunk) * H_ + h;
    *reinterpret_cast<float2*>(&aprod[idx]) = make_float2(a0, a1);
    *reinterpret_cast<float2*>(&cend[idx])  = make_float2(c0, c1);
}

__global__ void scan_p2(const float* __restrict__ aprod, const float* __restrict__ cend,
                        float* __restrict__ cin, float* __restrict__ hout, int layer) {
    const int b = blockIdx.x >> 2;
    const int h = ((blockIdx.x & 3) << 8) + threadIdx.x;
    float c = 0.f;
    #pragma unroll
    for (int k = 0; k < NC_; ++k) {
        const size_t idx = ((size_t)b * NC_ + k) * H_ + h;
        cin[idx] = c;
        c = aprod[idx] * c + cend[idx];
    }
    hout[(size_t)(((b << 1) + layer) << 10) + h] = c;
}

__global__ void scan_p3(const u16* __restrict__ y, const float* __restrict__ cin,
                        void* __restrict__ xout, int layer) {
    const int hb = blockIdx.x & 1;
    const int chunk = (blockIdx.x >> 1) & (NC_ - 1);
    const int b = blockIdx.x >> 7;
    const int h = (hb << 9) + (threadIdx.x << 1);
    const u16* yb = y + ((size_t)b * T_ + (size_t)chunk * L_) * N_;
    const size_t cidx = ((size_t)b * NC_ + chunk) * H_ + h;
    const float2 cv = *reinterpret_cast<const float2*>(&cin[cidx]);
    float c0 = cv.x, c1 = cv.y;
    u32*    xo_bf = (u32*)xout;
    float2* xo_f  = (float2*)xout;
    const size_t obase = ((size_t)b * T_ + (size_t)chunk * L_) * H_ + h;
    #pragma unroll 4
    for (int t = 0; t < L_; ++t) {
        const u32 zz = *reinterpret_cast<const u32*>(&yb[t * N_ + h]);
        const u32 ff = *reinterpret_cast<const u32*>(&yb[t * N_ + H_ + h]);
        const u32 oo = *reinterpret_cast<const u32*>(&yb[t * N_ + 2 * H_ + h]);
        const float f0 = sigm(bf2f((u16)ff));
        const float f1 = sigm(bf2f((u16)(ff >> 16)));
        const float z0 = fmaxf(bf2f((u16)zz), 0.f);
        const float z1 = fmaxf(bf2f((u16)(zz >> 16)), 0.f);
        c0 = f0 * z0 + (1.f - f0) * c0;
        c1 = f1 * z1 + (1.f - f1) * c1;
        const float o0 = sigm(bf2f((u16)oo)) * c0;
        const float o1 = sigm(bf2f((u16)(oo >> 16))) * c1;
        const size_t oi = obase + (size_t)t * H_;
        if (layer) xo_f[oi >> 1] = make_float2(o0, o1);
        else       xo_bf[oi >> 1] = (u32)f2bf(o0) | ((u32)f2bf(o1) << 16);
    }
}

extern "C" void kernel_launch(void* const* d_in, const int* in_sizes, int n_in,
                              void* d_out, int out_size, void* d_ws, size_t ws_size,
                              hipStream_t stream) {
    const float* pa = (const float*)d_in[0];
    const float* st = (const float*)d_in[1];
    const float* md = (const float*)d_in[2];
    const float* W1 = (const float*)d_in[3];
    const float* b1 = (const float*)d_in[4];
    const float* W2 = (const float*)d_in[5];
    const float* b2 = (const float*)d_in[6];
    float* out = (float*)d_out;

    char* ws = (char*)d_ws;
    const size_t y_bytes = (size_t)M_ * N_ * 2;          // 100.7 MB
    const size_t x_bytes = (size_t)M_ * 1600 * 2;        // 52.4 MB
    u16* y  = (u16*)ws;
    u16* x  = (u16*)(ws + y_bytes);
    u16* Wt = (u16*)(ws + y_bytes + x_bytes);            // 9.8 MB
    char* scr = ws + y_bytes + (size_t)M_ * H_ * 2;      // tail of x buffer (18.9MB free)
    const size_t sarr = (size_t)B_ * NC_ * H_ * 4;       // 2 MB each
    float* aprod = (float*)scr;
    float* cend  = (float*)(scr + sarr);
    float* cin   = (float*)(scr + 2 * sarr);

    float* hout = out + (size_t)M_ * H_;

    const int grid_g = (M_ / 256) * (N_ / 256);          // 64*12 = 768 (%8==0)

    // ---- layer 1 ----
    concat_cast<<<M_, 256, 0, stream>>>(pa, st, md, x);
    wtrans<<<dim3(N_ / 32, 50), 256, 0, stream>>>(W1, Wt, 1591, 1600);
    gemm8p<<<grid_g, 512, 0, stream>>>(x, Wt, b1, y, 1600, 50, N_ / 256);
    scan_p1<<<B_ * NC_ * 2, 256, 0, stream>>>(y, aprod, cend);
    scan_p2<<<32, 256, 0, stream>>>(aprod, cend, cin, hout, 0);
    scan_p3<<<B_ * NC_ * 2, 256, 0, stream>>>(y, cin, x, 0);   // bf16 x2 into x

    // ---- layer 2 ----
    wtrans<<<dim3(N_ / 32, 32), 256, 0, stream>>>(W2, Wt, 1024, 1024);
    gemm8p<<<grid_g, 512, 0, stream>>>(x, Wt, b2, y, 1024, 32, N_ / 256);
    scan_p1<<<B_ * NC_ * 2, 256, 0, stream>>>(y, aprod, cend);
    scan_p2<<<32, 256, 0, stream>>>(aprod, cend, cin, hout, 1);
    scan_p3<<<B_ * NC_ * 2, 256, 0, stream>>>(y, cin, out, 1);
}